// Round 3
// baseline (488.803 us; speedup 1.0000x reference)
//
#include <hip/hip_runtime.h>
#include <hip/hip_bf16.h>
#include <math.h>

#define HDIM 768
#define NHEAD 12
#define HEADD 64
#define FFDIM 3072
#define NEXP 4
#define SEQ 128
#define NB 64
#define QKVN 2304

typedef __attribute__((ext_vector_type(8))) _Float16 f16x8;
typedef __attribute__((ext_vector_type(4))) _Float16 f16x4;
typedef __attribute__((ext_vector_type(4))) float f32x4;

// s_waitcnt encodings: vm low [3:0], exp [6:4], lgkm [11:8], vm high [15:14]
#define WAITVM3 __builtin_amdgcn_s_waitcnt(0xF73)   // vmcnt(3), lgkm/exp untouched
#define WAITVM0 __builtin_amdgcn_s_waitcnt(0xF70)   // vmcnt(0)
#define WAITLGKM0 __builtin_amdgcn_s_waitcnt(0xC07F) // lgkmcnt(0), vm untouched

// gelu_tanh(x) = x * sigmoid(1.5957691*x*(1+0.044715x^2)) — exact rewrite
__device__ __forceinline__ float gelu_fast(float x) {
  float t = -1.5957691216057308f * x * __builtin_fmaf(0.044715f * x, x, 1.0f);
  return x * __builtin_amdgcn_rcpf(1.0f + __expf(t));
}

__device__ __forceinline__ void gld_lds16(const void* g, void* l) {
  __builtin_amdgcn_global_load_lds(
      (const __attribute__((address_space(1))) unsigned int*)g,
      (__attribute__((address_space(3))) unsigned int*)l, 16, 0, 0);
}

// ---------------- routing + fp32->f16 conversion (fused) ----------------------
__global__ __launch_bounds__(256) void route_cvt_kernel(
    const float* __restrict__ hs, const float* __restrict__ centers,
    int* __restrict__ eid, _Float16* __restrict__ x16) {
  int b = blockIdx.x, t = threadIdx.x;
  __shared__ float hp[HDIM];
  __shared__ float dist[NEXP];
  const float* xb = hs + (size_t)b * SEQ * HDIM;
  _Float16* ob = x16 + (size_t)b * SEQ * HDIM;

  if (t < 192) {
    float p0 = 0.f, p1 = 0.f, p2 = 0.f, p3 = 0.f;
    for (int sq = 0; sq < SEQ; ++sq) {
      float4 v = ((const float4*)(xb + (size_t)sq * HDIM))[t];
      p0 += v.x; p1 += v.y; p2 += v.z; p3 += v.w;
      f16x4 h = {(_Float16)v.x, (_Float16)v.y, (_Float16)v.z, (_Float16)v.w};
      *(f16x4*)(ob + (size_t)sq * HDIM + t * 4) = h;
    }
    hp[t * 4 + 0] = p0 * (1.0f / SEQ);
    hp[t * 4 + 1] = p1 * (1.0f / SEQ);
    hp[t * 4 + 2] = p2 * (1.0f / SEQ);
    hp[t * 4 + 3] = p3 * (1.0f / SEQ);
  }
  if (t < NEXP) dist[t] = 0.f;
  __syncthreads();

  float pe[NEXP] = {0.f, 0.f, 0.f, 0.f};
  for (int h = t; h < HDIM; h += 256) {
    float v = hp[h];
#pragma unroll
    for (int e = 0; e < NEXP; ++e) {
      float d = v - centers[e * HDIM + h];
      pe[e] += d * d;
    }
  }
#pragma unroll
  for (int e = 0; e < NEXP; ++e) atomicAdd(&dist[e], pe[e]);
  __syncthreads();
  if (t == 0) {
    int best = 0; float bv = dist[0];
    for (int e = 1; e < NEXP; ++e) if (dist[e] < bv) { bv = dist[e]; best = e; }
    eid[b] = best;
  }
}

// ---------------- ALL weight prep in one launch -------------------------------
__device__ __forceinline__ void tr_tile(const float* __restrict__ ip,
                                        _Float16* __restrict__ op,
                                        int K, int N, int nb, int kb,
                                        float (*tile)[33], int t) {
  int tx = t & 31, ty = t >> 5;
  for (int i = ty; i < 32; i += 8)
    tile[i][tx] = ip[(size_t)(kb + i) * N + nb + tx];
  __syncthreads();
  for (int i = ty; i < 32; i += 8)
    op[(size_t)(nb + i) * K + kb + tx] = (_Float16)tile[tx][i];
}

__global__ __launch_bounds__(256) void prep_weights(
    const float* __restrict__ wq, const float* __restrict__ wk,
    const float* __restrict__ wv, const float* __restrict__ wo,
    const float* __restrict__ w1, const float* __restrict__ w2,
    const float* __restrict__ bq, const float* __restrict__ bk,
    const float* __restrict__ bv,
    _Float16* __restrict__ Wqkvt, _Float16* __restrict__ Wot,
    _Float16* __restrict__ W1t, _Float16* __restrict__ W2t,
    float* __restrict__ bqkv, const int* __restrict__ eid,
    int* __restrict__ order, int* __restrict__ ord_eid) {
  __shared__ float tile[32][33];
  int x = blockIdx.x, e = blockIdx.y, t = threadIdx.x;

  if (x < 1728) {
    int which = x / 576, local = x % 576;
    const float* src = (which == 0) ? wq : (which == 1) ? wk : wv;
    tr_tile(src + (size_t)e * HDIM * HDIM,
            Wqkvt + (size_t)which * HDIM * HDIM + (size_t)e * QKVN * HDIM,
            HDIM, HDIM, (local % 24) * 32, (local / 24) * 32, tile, t);
  } else if (x < 2304) {
    int local = x - 1728;
    tr_tile(wo + (size_t)e * HDIM * HDIM, Wot + (size_t)e * HDIM * HDIM,
            HDIM, HDIM, (local % 24) * 32, (local / 24) * 32, tile, t);
  } else if (x < 4608) {
    int local = x - 2304;
    tr_tile(w1 + (size_t)e * HDIM * FFDIM, W1t + (size_t)e * FFDIM * HDIM,
            HDIM, FFDIM, (local % 96) * 32, (local / 96) * 32, tile, t);
  } else if (x < 6912) {
    int local = x - 4608;
    tr_tile(w2 + (size_t)e * FFDIM * HDIM, W2t + (size_t)e * HDIM * FFDIM,
            FFDIM, HDIM, (local % 24) * 32, (local / 24) * 32, tile, t);
  } else if (x < 6948) {
    if (e == 0) {
      int i = (x - 6912) * 256 + t;
      if (i < NEXP * QKVN) {
        int ee = i / QKVN, n = i % QKVN;
        float v = (n < HDIM) ? bq[ee * HDIM + n]
                : (n < 2 * HDIM) ? bk[ee * HDIM + n - HDIM]
                                 : bv[ee * HDIM + n - 2 * HDIM];
        bqkv[i] = v;
      }
    }
  } else {
    if (e == 0 && t == 0) {
      int n = 0;
      for (int ee = 0; ee < NEXP; ++ee)
        for (int b = 0; b < NB; ++b)
          if (eid[b] == ee) { order[n] = b; ord_eid[n] = ee; n++; }
    }
  }
}

// ---------------- MFMA GEMM: 128x256 tile, phase-split schedule ---------------
// r0-r2 evidence: 2-phase loop pinned at MfmaUtil ~21-22% under BOTH memory
// regimes (B-L2-resident vs not) -> schedule-bound, not memory-bound (m233
// signature: stage+vmcnt+barrier lump on critical path). This is the m201
// 8-phase template adapted: BM=128 BN=256 BK=64, 8 waves (2Mx4N, 64x64 each),
// 2 phases per K-tile (one per kk-half, 16 MFMA + 8 ds_read each), half-tile
// staging (3 gld_lds each), counted vmcnt(3) at phase ends — NEVER 0 mid-loop
// — and s_setprio(1) around each MFMA cluster (T5 pays only with phase-split).
// 96KB dynamic LDS (2 buffers x 48KB), 1 block/CU.
template <int OUT_F16, int GELU, int KDIM, int SPLITK>
__global__ __launch_bounds__(512, 2) void gemm_mfma8(
    const _Float16* __restrict__ A, const _Float16* __restrict__ Wt,
    const float* __restrict__ Ball, const int* __restrict__ order,
    const int* __restrict__ ord_eid, void* __restrict__ Cv, int N) {
  constexpr int K = KDIM;
  constexpr int Kp = KDIM / SPLITK;
  constexpr int NT = Kp / 64;
  extern __shared__ __align__(16) char dynlds[];
  _Float16* lds = (_Float16*)dynlds;

  int GX = N >> 8;
  int nwg = GX * NB * SPLITK;
  // XCD-locality remap (bijective: nwg % 8 == 0 for all shapes here)
  int L = blockIdx.x;
  int r = (L & 7) * (nwg >> 3) + (L >> 3);
  int z = r & 63;                      // sample index (expert-sorted), fastest
  int rest = r >> 6;
  int kz = rest % SPLITK;
  int c = rest / SPLITK;
  int b = order[z];
  int e = ord_eid[z];
  int col0 = c * 256;
  int kbeg = kz * Kp;

  int t = threadIdx.x;
  int lane = t & 63, w = t >> 6;
  int quad = lane >> 4, l16 = lane & 15;
  int wr64 = (w >> 2) * 64;            // wave row base (0/64)
  int wc64 = (w & 3) * 64;             // wave col base (0..192)

  // staging source addresses: thread t stages LDS row r0=t>>2, stored chunk
  // p=t&3 which must hold SOURCE chunk c = p ^ (r0&3) ^ ((r0>>2)&3)
  int csw = ((t & 3) ^ ((t >> 2) & 3) ^ ((t >> 4) & 3)) * 8;
  int r0 = t >> 2;

  const _Float16* srcA = A + (size_t)b * SEQ * K + kbeg + (size_t)r0 * K + csw;
  const _Float16* srcB0 = Wt + (size_t)e * N * K + (size_t)(col0 + r0) * K + kbeg + csw;
  const _Float16* srcB1 = srcB0 + (size_t)128 * K;

  // LDS layout (f16 elems): buffer bi at bi*24576; A halves at +kk*4096;
  // B at +8192, halves at +kk*8192 (B rows 0-127 then 128-255 within half)
  auto issueH = [&](int Tn, int h) {
    _Float16* dst = lds + (size_t)(Tn & 1) * 24576;
    int goff = Tn * 64 + h * 32;
    gld_lds16(srcA + goff, dst + h * 4096 + t * 8);
    gld_lds16(srcB0 + goff, dst + 8192 + h * 8192 + t * 8);
    gld_lds16(srcB1 + goff, dst + 8192 + h * 8192 + 4096 + t * 8);
  };

  f32x4 acc[4][4];
#pragma unroll
  for (int i = 0; i < 4; ++i)
#pragma unroll
    for (int j = 0; j < 4; ++j) acc[i][j] = (f32x4){0.f, 0.f, 0.f, 0.f};

  // read-side swizzle: per-lane constant chunk index
  int sl = (l16 & 3) ^ ((l16 >> 2) & 3);
  int ck8 = (quad ^ sl) * 8;

  // prologue: stage both halves of tile 0; drain H0(0) (H1 stays in flight)
  issueH(0, 0);
  issueH(0, 1);
  WAITVM3;
  __builtin_amdgcn_s_barrier();

#pragma unroll 2
  for (int T = 0; T < NT; ++T) {
    int bi = T & 1;
    const _Float16* Ab = lds + (size_t)bi * 24576;
    const _Float16* Bb = Ab + 8192;

    // ---- phase 0: kk=0 ----
    {
      f16x8 af[4], bf[4];
#pragma unroll
      for (int i = 0; i < 4; ++i)
        af[i] = *(const f16x8*)&Ab[(wr64 + i * 16 + l16) * 32 + ck8];
#pragma unroll
      for (int j = 0; j < 4; ++j)
        bf[j] = *(const f16x8*)&Bb[(wc64 + j * 16 + l16) * 32 + ck8];
      if (T + 1 < NT) issueH(T + 1, 0);
      __builtin_amdgcn_s_barrier();
      WAITLGKM0;
      __builtin_amdgcn_s_setprio(1);
#pragma unroll
      for (int i = 0; i < 4; ++i)
#pragma unroll
        for (int j = 0; j < 4; ++j)
          acc[i][j] = __builtin_amdgcn_mfma_f32_16x16x32_f16(af[i], bf[j], acc[i][j], 0, 0, 0);
      __builtin_amdgcn_s_setprio(0);
      if (T + 1 < NT) WAITVM3;   // drain H1(T); H0(T+1) stays in flight
      else            WAITVM0;   // last tile: only H1(T) outstanding
      __builtin_amdgcn_s_barrier();
    }

    // ---- phase 1: kk=1 ----
    {
      const _Float16* Ab1 = Ab + 4096;
      const _Float16* Bb1 = Bb + 8192;
      f16x8 af[4], bf[4];
#pragma unroll
      for (int i = 0; i < 4; ++i)
        af[i] = *(const f16x8*)&Ab1[(wr64 + i * 16 + l16) * 32 + ck8];
#pragma unroll
      for (int j = 0; j < 4; ++j)
        bf[j] = *(const f16x8*)&Bb1[(wc64 + j * 16 + l16) * 32 + ck8];
      if (T + 1 < NT) issueH(T + 1, 1);
      __builtin_amdgcn_s_barrier();
      WAITLGKM0;
      __builtin_amdgcn_s_setprio(1);
#pragma unroll
      for (int i = 0; i < 4; ++i)
#pragma unroll
        for (int j = 0; j < 4; ++j)
          acc[i][j] = __builtin_amdgcn_mfma_f32_16x16x32_f16(af[i], bf[j], acc[i][j], 0, 0, 0);
      __builtin_amdgcn_s_setprio(0);
      if (T + 1 < NT) {
        WAITVM3;                 // drain H0(T+1); H1(T+1) stays in flight
        __builtin_amdgcn_s_barrier();
      }
    }
  }

  const float* bias = Ball + (size_t)e * N;

  if (OUT_F16) {
    _Float16* Ch = (_Float16*)Cv + (size_t)b * SEQ * N;
#pragma unroll
    for (int i = 0; i < 4; ++i)
#pragma unroll
      for (int j = 0; j < 4; ++j) {
        int col = col0 + wc64 + j * 16 + l16;
        float bv = bias[col];
#pragma unroll
        for (int r2 = 0; r2 < 4; ++r2) {
          int row = wr64 + i * 16 + quad * 4 + r2;
          float v = acc[i][j][r2] + bv;
          if (GELU) v = gelu_fast(v);
          Ch[(size_t)row * N + col] = (_Float16)v;
        }
      }
  } else {
    float* Cf = (float*)Cv + (size_t)kz * NB * SEQ * N + (size_t)b * SEQ * N;
    float bscale = (kz == 0) ? 1.f : 0.f;
#pragma unroll
    for (int i = 0; i < 4; ++i)
#pragma unroll
      for (int j = 0; j < 4; ++j) {
        int col = col0 + wc64 + j * 16 + l16;
        float bv = bias[col] * bscale;
#pragma unroll
        for (int r2 = 0; r2 < 4; ++r2) {
          int row = wr64 + i * 16 + quad * 4 + r2;
          Cf[(size_t)row * N + col] = acc[i][j][r2] + bv;
        }
      }
  }
}

// ---------------- MFMA attention: one block per (head, sample) ----------------
__global__ __launch_bounds__(256) void attn_mfma(
    const _Float16* __restrict__ QKV, const float* __restrict__ mask,
    _Float16* __restrict__ Ctx) {
  int h = blockIdx.x, b = blockIdx.y;
  int t = threadIdx.x;
  int w = t >> 6, lane = t & 63, quad = lane >> 4, l16 = lane & 15;

  __shared__ __align__(16) char smem[54784];
  _Float16* Qs = (_Float16*)smem;                 // [128][72]
  _Float16* Ks = (_Float16*)(smem + 18432);       // [128][72]
  _Float16* Ps = (_Float16*)smem;                 // [128][136]
  _Float16* Vt = (_Float16*)(smem + 36864);       // [64][136]
  float* mrow = (float*)(smem + 54272);           // [128]

  const _Float16* Qb = QKV + (size_t)b * SEQ * QKVN + h * HEADD;
  const _Float16* Kb = Qb + HDIM;
  const _Float16* Vb = Qb + 2 * HDIM;

#pragma unroll
  for (int it = 0; it < 4; ++it) {
    int chunk = t + it * 256;
    int row = chunk >> 3, c = chunk & 7;
    *(f16x8*)&Qs[row * 72 + c * 8] = *(const f16x8*)(Qb + (size_t)row * QKVN + c * 8);
    *(f16x8*)&Ks[row * 72 + c * 8] = *(const f16x8*)(Kb + (size_t)row * QKVN + c * 8);
  }
  {
    int vc = t & 7, vjp0 = t >> 3;
#pragma unroll
    for (int it = 0; it < 2; ++it) {
      int jp = vjp0 + it * 32;
      f16x8 v0 = *(const f16x8*)(Vb + (size_t)(2 * jp) * QKVN + vc * 8);
      f16x8 v1 = *(const f16x8*)(Vb + (size_t)(2 * jp + 1) * QKVN + vc * 8);
#pragma unroll
      for (int i = 0; i < 8; ++i) {
        int d = vc * 8 + i;
        unsigned ua = __builtin_bit_cast(unsigned short, (_Float16)v0[i]);
        unsigned ub = __builtin_bit_cast(unsigned short, (_Float16)v1[i]);
        ((unsigned*)Vt)[d * 68 + jp] = ua | (ub << 16);
      }
    }
  }
  if (t < SEQ) mrow[t] = mask[(size_t)b * SEQ + t];
  __syncthreads();

  int m0 = w * 32;
  f32x4 accs[2][8];
#pragma unroll
  for (int i = 0; i < 2; ++i)
#pragma unroll
    for (int j = 0; j < 8; ++j) accs[i][j] = (f32x4){0.f, 0.f, 0.f, 0.f};

#pragma unroll
  for (int ks = 0; ks < 2; ++ks) {
    int k0 = ks * 32 + quad * 8;
    f16x8 af[2], bf[8];
#pragma unroll
    for (int i = 0; i < 2; ++i)
      af[i] = *(const f16x8*)&Qs[(m0 + i * 16 + l16) * 72 + k0];
#pragma unroll
    for (int j = 0; j < 8; ++j)
      bf[j] = *(const f16x8*)&Ks[(j * 16 + l16) * 72 + k0];
#pragma unroll
    for (int i = 0; i < 2; ++i)
#pragma unroll
      for (int j = 0; j < 8; ++j)
        accs[i][j] = __builtin_amdgcn_mfma_f32_16x16x32_f16(af[i], bf[j], accs[i][j], 0, 0, 0);
  }
  __syncthreads();

  float mv[8];
#pragma unroll
  for (int j = 0; j < 8; ++j) mv[j] = mrow[j * 16 + l16];

  float linv[2][4];
#pragma unroll
  for (int i = 0; i < 2; ++i) {
#pragma unroll
    for (int j = 0; j < 8; ++j)
#pragma unroll
      for (int r = 0; r < 4; ++r)
        accs[i][j][r] = accs[i][j][r] * 0.125f + mv[j];
#pragma unroll
    for (int r = 0; r < 4; ++r) {
      float m = accs[i][0][r];
#pragma unroll
      for (int j = 1; j < 8; ++j) m = fmaxf(m, accs[i][j][r]);
      m = fmaxf(m, __shfl_xor(m, 1));
      m = fmaxf(m, __shfl_xor(m, 2));
      m = fmaxf(m, __shfl_xor(m, 4));
      m = fmaxf(m, __shfl_xor(m, 8));
      float sum = 0.f;
#pragma unroll
      for (int j = 0; j < 8; ++j) {
        float p = __expf(accs[i][j][r] - m);
        accs[i][j][r] = p;
        sum += p;
      }
      sum += __shfl_xor(sum, 1);
      sum += __shfl_xor(sum, 2);
      sum += __shfl_xor(sum, 4);
      sum += __shfl_xor(sum, 8);
      linv[i][r] = 1.f / sum;
    }
    int rowb = m0 + i * 16 + quad * 4;
#pragma unroll
    for (int j = 0; j < 8; ++j)
#pragma unroll
      for (int r = 0; r < 4; ++r)
        Ps[(rowb + r) * 136 + j * 16 + l16] = (_Float16)accs[i][j][r];
  }
  __syncthreads();

  f32x4 acco[2][4];
#pragma unroll
  for (int i = 0; i < 2; ++i)
#pragma unroll
    for (int j = 0; j < 4; ++j) acco[i][j] = (f32x4){0.f, 0.f, 0.f, 0.f};

#pragma unroll
  for (int ks = 0; ks < 4; ++ks) {
    int k0 = ks * 32 + quad * 8;
    f16x8 pa[2], vf[4];
#pragma unroll
    for (int i = 0; i < 2; ++i)
      pa[i] = *(const f16x8*)&Ps[(m0 + i * 16 + l16) * 136 + k0];
#pragma unroll
    for (int j = 0; j < 4; ++j)
      vf[j] = *(const f16x8*)&Vt[(j * 16 + l16) * 136 + k0];
#pragma unroll
    for (int i = 0; i < 2; ++i)
#pragma unroll
      for (int j = 0; j < 4; ++j)
        acco[i][j] = __builtin_amdgcn_mfma_f32_16x16x32_f16(pa[i], vf[j], acco[i][j], 0, 0, 0);
  }

  _Float16* Cb = Ctx + (size_t)b * SEQ * HDIM + h * HEADD;
#pragma unroll
  for (int i = 0; i < 2; ++i)
#pragma unroll
    for (int j = 0; j < 4; ++j)
#pragma unroll
      for (int r = 0; r < 4; ++r) {
        int row = m0 + i * 16 + quad * 4 + r;
        int d = j * 16 + l16;
        Cb[(size_t)row * HDIM + d] = (_Float16)(acco[i][j][r] * linv[i][r]);
      }
}

// ---------------- residual + NP partials + layernorm ---------------------------
template <int NP>
__global__ __launch_bounds__(256) void resid_ln_kernel(
    const float* __restrict__ X, const float* __restrict__ P0,
    const float* __restrict__ P1,
    const float* __restrict__ Gall, const float* __restrict__ Ball,
    const int* __restrict__ eid, float* __restrict__ Out,
    _Float16* __restrict__ Out16) {
  int row = blockIdx.x, b = blockIdx.y, t = threadIdx.x;
  int e = eid[b];
  size_t off = ((size_t)b * SEQ + row) * HDIM;
  const float* x = X + off;
  const float* p0 = P0 + off;
  const float* p1 = (NP > 1) ? P1 + off : nullptr;
  float* o = Out + off;
  const float* g = Gall + (size_t)e * HDIM;
  const float* bb = Ball + (size_t)e * HDIM;

  __shared__ float buf[HDIM];
  __shared__ float red[256];

  float s = 0.f;
  for (int h = t; h < HDIM; h += 256) {
    float v = x[h] + p0[h];
    if (NP > 1) v += p1[h];
    buf[h] = v;
    s += v;
  }
  red[t] = s;
  __syncthreads();
  for (int off2 = 128; off2 > 0; off2 >>= 1) {
    if (t < off2) red[t] += red[t + off2];
    __syncthreads();
  }
  float mean = red[0] * (1.0f / HDIM);
  __syncthreads();

  float s2 = 0.f;
  for (int h = t; h < HDIM; h += 256) {
    float d = buf[h] - mean;
    s2 += d * d;
  }
  red[t] = s2;
  __syncthreads();
  for (int off2 = 128; off2 > 0; off2 >>= 1) {
    if (t < off2) red[t] += red[t + off2];
    __syncthreads();
  }
  float var = red[0] * (1.0f / HDIM);
  float rs = rsqrtf(var + 1e-12f);

  for (int h = t; h < HDIM; h += 256) {
    float v = (buf[h] - mean) * rs * g[h] + bb[h];
    o[h] = v;
    if (Out16) Out16[off + h] = (_Float16)v;
  }
}

// ------------------------------------------------------------------------------
extern "C" void kernel_launch(void* const* d_in, const int* in_sizes, int n_in,
                              void* d_out, int out_size, void* d_ws, size_t ws_size,
                              hipStream_t stream) {
  const float* hs   = (const float*)d_in[0];
  const float* mask = (const float*)d_in[1];
  const float* cen  = (const float*)d_in[2];
  const float* wq = (const float*)d_in[3];
  const float* wk = (const float*)d_in[4];
  const float* wv = (const float*)d_in[5];
  const float* wo = (const float*)d_in[6];
  const float* bq = (const float*)d_in[7];
  const float* bk = (const float*)d_in[8];
  const float* bv = (const float*)d_in[9];
  const float* bo = (const float*)d_in[10];
  const float* ln1g = (const float*)d_in[11];
  const float* ln1b = (const float*)d_in[12];
  const float* w1 = (const float*)d_in[13];
  const float* b1 = (const float*)d_in[14];
  const float* w2 = (const float*)d_in[15];
  const float* b2 = (const float*)d_in[16];
  const float* ln2g = (const float*)d_in[17];
  const float* ln2b = (const float*)d_in[18];
  float* out = (float*)d_out;

  const size_t sh = (size_t)SEQ * HDIM;
  const int DYNLDS = 98304;  // 96 KB

  // raise the dynamic-LDS cap once per process (gfx950 supports 160 KB/CU;
  // 128 KB/block verified in plain HIP on MI355X)
  static bool attr_done = false;
  if (!attr_done) {
    attr_done = true;
    auto* k1 = gemm_mfma8<1, 0, HDIM, 1>;
    auto* k2 = gemm_mfma8<0, 0, HDIM, 2>;
    auto* k3 = gemm_mfma8<1, 1, HDIM, 1>;
    auto* k4 = gemm_mfma8<0, 0, FFDIM, 2>;
    (void)hipFuncSetAttribute((const void*)k1, hipFuncAttributeMaxDynamicSharedMemorySize, DYNLDS);
    (void)hipFuncSetAttribute((const void*)k2, hipFuncAttributeMaxDynamicSharedMemorySize, DYNLDS);
    (void)hipFuncSetAttribute((const void*)k3, hipFuncAttributeMaxDynamicSharedMemorySize, DYNLDS);
    (void)hipFuncSetAttribute((const void*)k4, hipFuncAttributeMaxDynamicSharedMemorySize, DYNLDS);
  }

  char* p = (char*)d_ws;
  int* eid = (int*)p;                 p += 256;
  int* order = (int*)p;               p += 256;
  int* ord_eid = (int*)p;             p += 256;
  float* bqkv = (float*)p;            p += (size_t)NEXP * QKVN * 4;
  _Float16* Wqkvt = (_Float16*)p;     p += (size_t)NEXP * QKVN * HDIM * 2;
  _Float16* Wot = (_Float16*)p;       p += (size_t)NEXP * HDIM * HDIM * 2;
  _Float16* W1t = (_Float16*)p;       p += (size_t)NEXP * FFDIM * HDIM * 2;
  _Float16* W2t = (_Float16*)p;       p += (size_t)NEXP * HDIM * FFDIM * 2;
  _Float16* x16 = (_Float16*)p;       p += (size_t)NB * sh * 2;

  char* region = p;                   p += (size_t)NB * SEQ * QKVN * 2;
  _Float16* ctx16 = (_Float16*)p;     p += (size_t)NB * sh * 2;
  float* aof = (float*)p;             p += (size_t)NB * sh * 4;
  _Float16* ao16 = (_Float16*)p;      p += (size_t)NB * sh * 2;
  char* ffreg = p;                    p += (size_t)NB * SEQ * FFDIM * 2;

  float* woparts = (float*)ffreg;
  float* w2parts = (float*)region;
  _Float16* ff16 = (_Float16*)ffreg;

  // 1. routing + hs->f16
  route_cvt_kernel<<<NB, 256, 0, stream>>>(hs, cen, eid, x16);
  // 2. weight prep (single launch)
  prep_weights<<<dim3(6949, NEXP), 256, 0, stream>>>(
      wq, wk, wv, wo, w1, w2, bq, bk, bv,
      Wqkvt, Wot, W1t, W2t, bqkv, eid, order, ord_eid);
  // 3. QKV fused -> region (f16): 9 col-tiles x 64 samples = 576 blocks
  gemm_mfma8<1, 0, HDIM, 1><<<dim3((QKVN / 256) * NB), 512, DYNLDS, stream>>>(
      x16, Wqkvt, bqkv, order, ord_eid, region, QKVN);
  // 4. attention -> ctx16
  attn_mfma<<<dim3(NHEAD, NB), 256, 0, stream>>>(
      (const _Float16*)region, mask, ctx16);
  // 5. wo split-K=2 -> woparts (ffreg): 3 x 64 x 2 = 384 blocks
  gemm_mfma8<0, 0, HDIM, 2><<<dim3((HDIM / 256) * NB * 2), 512, DYNLDS, stream>>>(
      ctx16, Wot, bo, order, ord_eid, woparts, HDIM);
  // 6. LN1
  resid_ln_kernel<2><<<dim3(SEQ, NB), 256, 0, stream>>>(
      hs, woparts, woparts + (size_t)NB * sh, ln1g, ln1b, eid, aof, ao16);
  // 7. w1 + fast GELU -> ff16: 12 col-tiles x 64 = 768 blocks
  gemm_mfma8<1, 1, HDIM, 1><<<dim3((FFDIM / 256) * NB), 512, DYNLDS, stream>>>(
      ao16, W1t, b1, order, ord_eid, ff16, FFDIM);
  // 8. w2 split-K=2 -> w2parts: 384 blocks
  gemm_mfma8<0, 0, FFDIM, 2><<<dim3((HDIM / 256) * NB * 2), 512, DYNLDS, stream>>>(
      ff16, W2t, b2, order, ord_eid, w2parts, HDIM);
  // 9. LN2 -> out
  resid_ln_kernel<2><<<dim3(SEQ, NB), 256, 0, stream>>>(
      aof, w2parts, w2parts + (size_t)NB * sh, ln2g, ln2b, eid, out,
      (_Float16*)nullptr);
}

// Round 5
// 449.888 us; speedup vs baseline: 1.0865x; 1.0865x over previous
//
#include <hip/hip_runtime.h>
#include <hip/hip_bf16.h>
#include <math.h>

#define HDIM 768
#define NHEAD 12
#define HEADD 64
#define FFDIM 3072
#define NEXP 4
#define SEQ 128
#define NB 64
#define QKVN 2304

typedef __attribute__((ext_vector_type(8))) _Float16 f16x8;
typedef __attribute__((ext_vector_type(4))) _Float16 f16x4;
typedef __attribute__((ext_vector_type(4))) float f32x4;

// s_waitcnt encodings: vm low [3:0], exp [6:4], lgkm [11:8], vm high [15:14]
#define WAITVM0 __builtin_amdgcn_s_waitcnt(0xF70)    // vmcnt(0)
#define WAITLGKM0 __builtin_amdgcn_s_waitcnt(0xC07F) // lgkmcnt(0), vm untouched

// gelu_tanh(x) = x * sigmoid(1.5957691*x*(1+0.044715x^2)) — exact rewrite
__device__ __forceinline__ float gelu_fast(float x) {
  float t = -1.5957691216057308f * x * __builtin_fmaf(0.044715f * x, x, 1.0f);
  return x * __builtin_amdgcn_rcpf(1.0f + __expf(t));
}

__device__ __forceinline__ void gld_lds16(const void* g, void* l) {
  __builtin_amdgcn_global_load_lds(
      (const __attribute__((address_space(1))) unsigned int*)g,
      (__attribute__((address_space(3))) unsigned int*)l, 16, 0, 0);
}

// ---------------- routing + fp32->f16 conversion (fused) ----------------------
__global__ __launch_bounds__(256) void route_cvt_kernel(
    const float* __restrict__ hs, const float* __restrict__ centers,
    int* __restrict__ eid, _Float16* __restrict__ x16) {
  int b = blockIdx.x, t = threadIdx.x;
  __shared__ float hp[HDIM];
  __shared__ float dist[NEXP];
  const float* xb = hs + (size_t)b * SEQ * HDIM;
  _Float16* ob = x16 + (size_t)b * SEQ * HDIM;

  if (t < 192) {
    float p0 = 0.f, p1 = 0.f, p2 = 0.f, p3 = 0.f;
    for (int sq = 0; sq < SEQ; ++sq) {
      float4 v = ((const float4*)(xb + (size_t)sq * HDIM))[t];
      p0 += v.x; p1 += v.y; p2 += v.z; p3 += v.w;
      f16x4 h = {(_Float16)v.x, (_Float16)v.y, (_Float16)v.z, (_Float16)v.w};
      *(f16x4*)(ob + (size_t)sq * HDIM + t * 4) = h;
    }
    hp[t * 4 + 0] = p0 * (1.0f / SEQ);
    hp[t * 4 + 1] = p1 * (1.0f / SEQ);
    hp[t * 4 + 2] = p2 * (1.0f / SEQ);
    hp[t * 4 + 3] = p3 * (1.0f / SEQ);
  }
  if (t < NEXP) dist[t] = 0.f;
  __syncthreads();

  float pe[NEXP] = {0.f, 0.f, 0.f, 0.f};
  for (int h = t; h < HDIM; h += 256) {
    float v = hp[h];
#pragma unroll
    for (int e = 0; e < NEXP; ++e) {
      float d = v - centers[e * HDIM + h];
      pe[e] += d * d;
    }
  }
#pragma unroll
  for (int e = 0; e < NEXP; ++e) atomicAdd(&dist[e], pe[e]);
  __syncthreads();
  if (t == 0) {
    int best = 0; float bv = dist[0];
    for (int e = 1; e < NEXP; ++e) if (dist[e] < bv) { bv = dist[e]; best = e; }
    eid[b] = best;
  }
}

// ---------------- ALL weight prep in one launch -------------------------------
__device__ __forceinline__ void tr_tile(const float* __restrict__ ip,
                                        _Float16* __restrict__ op,
                                        int K, int N, int nb, int kb,
                                        float (*tile)[33], int t) {
  int tx = t & 31, ty = t >> 5;
  for (int i = ty; i < 32; i += 8)
    tile[i][tx] = ip[(size_t)(kb + i) * N + nb + tx];
  __syncthreads();
  for (int i = ty; i < 32; i += 8)
    op[(size_t)(nb + i) * K + kb + tx] = (_Float16)tile[tx][i];
}

__global__ __launch_bounds__(256) void prep_weights(
    const float* __restrict__ wq, const float* __restrict__ wk,
    const float* __restrict__ wv, const float* __restrict__ wo,
    const float* __restrict__ w1, const float* __restrict__ w2,
    const float* __restrict__ bq, const float* __restrict__ bk,
    const float* __restrict__ bv,
    _Float16* __restrict__ Wqkvt, _Float16* __restrict__ Wot,
    _Float16* __restrict__ W1t, _Float16* __restrict__ W2t,
    float* __restrict__ bqkv, const int* __restrict__ eid,
    int* __restrict__ order, int* __restrict__ ord_eid) {
  __shared__ float tile[32][33];
  int x = blockIdx.x, e = blockIdx.y, t = threadIdx.x;

  if (x < 1728) {
    int which = x / 576, local = x % 576;
    const float* src = (which == 0) ? wq : (which == 1) ? wk : wv;
    tr_tile(src + (size_t)e * HDIM * HDIM,
            Wqkvt + (size_t)which * HDIM * HDIM + (size_t)e * QKVN * HDIM,
            HDIM, HDIM, (local % 24) * 32, (local / 24) * 32, tile, t);
  } else if (x < 2304) {
    int local = x - 1728;
    tr_tile(wo + (size_t)e * HDIM * HDIM, Wot + (size_t)e * HDIM * HDIM,
            HDIM, HDIM, (local % 24) * 32, (local / 24) * 32, tile, t);
  } else if (x < 4608) {
    int local = x - 2304;
    tr_tile(w1 + (size_t)e * HDIM * FFDIM, W1t + (size_t)e * FFDIM * HDIM,
            HDIM, FFDIM, (local % 96) * 32, (local / 96) * 32, tile, t);
  } else if (x < 6912) {
    int local = x - 4608;
    tr_tile(w2 + (size_t)e * FFDIM * HDIM, W2t + (size_t)e * HDIM * FFDIM,
            FFDIM, HDIM, (local % 24) * 32, (local / 24) * 32, tile, t);
  } else if (x < 6948) {
    if (e == 0) {
      int i = (x - 6912) * 256 + t;
      if (i < NEXP * QKVN) {
        int ee = i / QKVN, n = i % QKVN;
        float v = (n < HDIM) ? bq[ee * HDIM + n]
                : (n < 2 * HDIM) ? bk[ee * HDIM + n - HDIM]
                                 : bv[ee * HDIM + n - 2 * HDIM];
        bqkv[i] = v;
      }
    }
  } else {
    if (e == 0 && t == 0) {
      int n = 0;
      for (int ee = 0; ee < NEXP; ++ee)
        for (int b = 0; b < NB; ++b)
          if (eid[b] == ee) { order[n] = b; ord_eid[n] = ee; n++; }
    }
  }
}

// ---------------- MFMA GEMM: 128x192 tile, st_16x32 LDS layout ----------------
// r0-r3: MfmaUtil pinned ~21-23% with EXACTLY 4.0 bank-conflict cyc per
// ds_read_b128 across all 64B-row layouts. m201 reference ([row][64] f16,
// 128B rows + st_16x32 col^=16 when row&4) measures ~0.04/read at 62%.
// r4 (144KB LDS) failed to launch -> same layout at a PROVEN footprint:
// BM=128 BN=192 BK=64, 8 waves (2x4, 64x48 tiles, 12 MFMA/phase), 2 buffers
// x 40KB = 80KB dynamic LDS -> 2 blocks/CU (cross-block overlap covers the
// rotate drain). 5 gld_lds16/tile (64-row chunks) issued 3+2 at the two
// phase issue-points of iter T for tile T+1; rotate = vmcnt(0)+barrier.
// Swizzle per rule #21: linear LDS dest, pre-swizzled global SOURCE col,
// matching XOR on the ds_read col (per-lane constant).
template <int OUT_F16, int GELU, int KDIM, int SPLITK>
__global__ __launch_bounds__(512, 4) void gemm_mfma8(
    const _Float16* __restrict__ A, const _Float16* __restrict__ Wt,
    const float* __restrict__ Ball, const int* __restrict__ order,
    const int* __restrict__ ord_eid, void* __restrict__ Cv, int N) {
  constexpr int K = KDIM;
  constexpr int Kp = KDIM / SPLITK;
  constexpr int NT = Kp / 64;
  extern __shared__ __align__(16) char dynlds[];
  _Float16* lds = (_Float16*)dynlds;

  int GX = N / 192;
  int nwg = GX * NB * SPLITK;
  // XCD-locality remap (bijective: nwg % 8 == 0 for all shapes here)
  int L = blockIdx.x;
  int r = (L & 7) * (nwg >> 3) + (L >> 3);
  int z = r & 63;                      // sample index (expert-sorted), fastest
  int rest = r >> 6;
  int kz = rest % SPLITK;
  int c = rest / SPLITK;
  int b = order[z];
  int e = ord_eid[z];
  int col0 = c * 192;
  int kbeg = kz * Kp;

  int t = threadIdx.x;
  int lane = t & 63, w = t >> 6;
  int quad = lane >> 4, l16 = lane & 15;
  int wr64 = (w >> 2) * 64;            // wave row base (0/64)
  int wc48 = (w & 3) * 48;             // wave col base (0/48/96/144)

  // staging: thread t fills 16B at linear LDS elem t*8 of a 64-row chunk
  // (row srow=t>>3, col (t&7)*8). st_16x32: that LDS slot must hold global
  // col ^ (16 when row&4); row bit2 of srow = t bit5.
  int srow = t >> 3;
  int scol = ((t & 7) * 8) ^ ((t & 32) >> 1);

  const _Float16* srcA = A + (size_t)b * SEQ * K + kbeg + (size_t)srow * K + scol;
  const _Float16* srcB = Wt + (size_t)e * N * K + (size_t)(col0 + srow) * K + kbeg + scol;

  // per-buffer f16 layout: A [128][64] at 0, B [192][64] at 8192. stride 20480.
  auto issueP0 = [&](int Tn) {   // 3 loads: A rows 0-63, A 64-127, B 0-63
    _Float16* dst = lds + (size_t)(Tn & 1) * 20480;
    int goff = Tn * 64;
    gld_lds16(srcA + goff, dst + t * 8);
    gld_lds16(srcA + (size_t)64 * K + goff, dst + 4096 + t * 8);
    gld_lds16(srcB + goff, dst + 8192 + t * 8);
  };
  auto issueP1 = [&](int Tn) {   // 2 loads: B rows 64-127, B 128-191
    _Float16* dst = lds + (size_t)(Tn & 1) * 20480;
    int goff = Tn * 64;
    gld_lds16(srcB + (size_t)64 * K + goff, dst + 12288 + t * 8);
    gld_lds16(srcB + (size_t)128 * K + goff, dst + 16384 + t * 8);
  };

  f32x4 acc[4][3];
#pragma unroll
  for (int i = 0; i < 4; ++i)
#pragma unroll
    for (int j = 0; j < 3; ++j) acc[i][j] = (f32x4){0.f, 0.f, 0.f, 0.f};

  // read-side swizzle: row = base16 + l16 -> row&4 = l16&4 (per-lane constant)
  int ck = (quad * 8) ^ ((l16 & 4) << 2);

  // prologue: stage tile 0, drain, sync
  issueP0(0);
  issueP1(0);
  WAITVM0;
  __builtin_amdgcn_s_barrier();

  for (int T = 0; T < NT; ++T) {
    const _Float16* Ab = lds + (size_t)(T & 1) * 20480;
    const _Float16* Bb = Ab + 8192;

    // ---- phase 0: kk=0 (cols 0-31) ----
    {
      f16x8 af[4], bf[3];
#pragma unroll
      for (int i = 0; i < 4; ++i)
        af[i] = *(const f16x8*)&Ab[(wr64 + i * 16 + l16) * 64 + ck];
#pragma unroll
      for (int j = 0; j < 3; ++j)
        bf[j] = *(const f16x8*)&Bb[(wc48 + j * 16 + l16) * 64 + ck];
      if (T + 1 < NT) issueP0(T + 1);
      __builtin_amdgcn_s_barrier();
      WAITLGKM0;
      __builtin_amdgcn_s_setprio(1);
#pragma unroll
      for (int i = 0; i < 4; ++i)
#pragma unroll
        for (int j = 0; j < 3; ++j)
          acc[i][j] = __builtin_amdgcn_mfma_f32_16x16x32_f16(af[i], bf[j], acc[i][j], 0, 0, 0);
      __builtin_amdgcn_s_setprio(0);
    }

    // ---- phase 1: kk=1 (cols 32-63) ----
    {
      f16x8 af[4], bf[3];
#pragma unroll
      for (int i = 0; i < 4; ++i)
        af[i] = *(const f16x8*)&Ab[(wr64 + i * 16 + l16) * 64 + 32 + ck];
#pragma unroll
      for (int j = 0; j < 3; ++j)
        bf[j] = *(const f16x8*)&Bb[(wc48 + j * 16 + l16) * 64 + 32 + ck];
      if (T + 1 < NT) issueP1(T + 1);
      __builtin_amdgcn_s_barrier();
      WAITLGKM0;
      __builtin_amdgcn_s_setprio(1);
#pragma unroll
      for (int i = 0; i < 4; ++i)
#pragma unroll
        for (int j = 0; j < 3; ++j)
          acc[i][j] = __builtin_amdgcn_mfma_f32_16x16x32_f16(af[i], bf[j], acc[i][j], 0, 0, 0);
      __builtin_amdgcn_s_setprio(0);
    }

    // rotate: tile T+1's 5 loads must have landed before next iter reads them
    if (T + 1 < NT) {
      WAITVM0;
      __builtin_amdgcn_s_barrier();
    }
  }

  const float* bias = Ball + (size_t)e * N;

  if (OUT_F16) {
    _Float16* Ch = (_Float16*)Cv + (size_t)b * SEQ * N;
#pragma unroll
    for (int i = 0; i < 4; ++i)
#pragma unroll
      for (int j = 0; j < 3; ++j) {
        int col = col0 + wc48 + j * 16 + l16;
        float bv = bias[col];
#pragma unroll
        for (int r2 = 0; r2 < 4; ++r2) {
          int row = wr64 + i * 16 + quad * 4 + r2;
          float v = acc[i][j][r2] + bv;
          if (GELU) v = gelu_fast(v);
          Ch[(size_t)row * N + col] = (_Float16)v;
        }
      }
  } else {
    float* Cf = (float*)Cv + (size_t)kz * NB * SEQ * N + (size_t)b * SEQ * N;
    float bscale = (kz == 0) ? 1.f : 0.f;
#pragma unroll
    for (int i = 0; i < 4; ++i)
#pragma unroll
      for (int j = 0; j < 3; ++j) {
        int col = col0 + wc48 + j * 16 + l16;
        float bv = bias[col] * bscale;
#pragma unroll
        for (int r2 = 0; r2 < 4; ++r2) {
          int row = wr64 + i * 16 + quad * 4 + r2;
          Cf[(size_t)row * N + col] = acc[i][j][r2] + bv;
        }
      }
  }
}

// ---------------- MFMA attention: one block per (head, sample) ----------------
__global__ __launch_bounds__(256) void attn_mfma(
    const _Float16* __restrict__ QKV, const float* __restrict__ mask,
    _Float16* __restrict__ Ctx) {
  int h = blockIdx.x, b = blockIdx.y;
  int t = threadIdx.x;
  int w = t >> 6, lane = t & 63, quad = lane >> 4, l16 = lane & 15;

  __shared__ __align__(16) char smem[54784];
  _Float16* Qs = (_Float16*)smem;                 // [128][72]
  _Float16* Ks = (_Float16*)(smem + 18432);       // [128][72]
  _Float16* Ps = (_Float16*)smem;                 // [128][136]
  _Float16* Vt = (_Float16*)(smem + 36864);       // [64][136]
  float* mrow = (float*)(smem + 54272);           // [128]

  const _Float16* Qb = QKV + (size_t)b * SEQ * QKVN + h * HEADD;
  const _Float16* Kb = Qb + HDIM;
  const _Float16* Vb = Qb + 2 * HDIM;

#pragma unroll
  for (int it = 0; it < 4; ++it) {
    int chunk = t + it * 256;
    int row = chunk >> 3, c = chunk & 7;
    *(f16x8*)&Qs[row * 72 + c * 8] = *(const f16x8*)(Qb + (size_t)row * QKVN + c * 8);
    *(f16x8*)&Ks[row * 72 + c * 8] = *(const f16x8*)(Kb + (size_t)row * QKVN + c * 8);
  }
  {
    int vc = t & 7, vjp0 = t >> 3;
#pragma unroll
    for (int it = 0; it < 2; ++it) {
      int jp = vjp0 + it * 32;
      f16x8 v0 = *(const f16x8*)(Vb + (size_t)(2 * jp) * QKVN + vc * 8);
      f16x8 v1 = *(const f16x8*)(Vb + (size_t)(2 * jp + 1) * QKVN + vc * 8);
#pragma unroll
      for (int i = 0; i < 8; ++i) {
        int d = vc * 8 + i;
        unsigned ua = __builtin_bit_cast(unsigned short, (_Float16)v0[i]);
        unsigned ub = __builtin_bit_cast(unsigned short, (_Float16)v1[i]);
        ((unsigned*)Vt)[d * 68 + jp] = ua | (ub << 16);
      }
    }
  }
  if (t < SEQ) mrow[t] = mask[(size_t)b * SEQ + t];
  __syncthreads();

  int m0 = w * 32;
  f32x4 accs[2][8];
#pragma unroll
  for (int i = 0; i < 2; ++i)
#pragma unroll
    for (int j = 0; j < 8; ++j) accs[i][j] = (f32x4){0.f, 0.f, 0.f, 0.f};

#pragma unroll
  for (int ks = 0; ks < 2; ++ks) {
    int k0 = ks * 32 + quad * 8;
    f16x8 af[2], bf[8];
#pragma unroll
    for (int i = 0; i < 2; ++i)
      af[i] = *(const f16x8*)&Qs[(m0 + i * 16 + l16) * 72 + k0];
#pragma unroll
    for (int j = 0; j < 8; ++j)
      bf[j] = *(const f16x8*)&Ks[(j * 16 + l16) * 72 + k0];
#pragma unroll
    for (int i = 0; i < 2; ++i)
#pragma unroll
      for (int j = 0; j < 8; ++j)
        accs[i][j] = __builtin_amdgcn_mfma_f32_16x16x32_f16(af[i], bf[j], accs[i][j], 0, 0, 0);
  }
  __syncthreads();

  float mv[8];
#pragma unroll
  for (int j = 0; j < 8; ++j) mv[j] = mrow[j * 16 + l16];

  float linv[2][4];
#pragma unroll
  for (int i = 0; i < 2; ++i) {
#pragma unroll
    for (int j = 0; j < 8; ++j)
#pragma unroll
      for (int r = 0; r < 4; ++r)
        accs[i][j][r] = accs[i][j][r] * 0.125f + mv[j];
#pragma unroll
    for (int r = 0; r < 4; ++r) {
      float m = accs[i][0][r];
#pragma unroll
      for (int j = 1; j < 8; ++j) m = fmaxf(m, accs[i][j][r]);
      m = fmaxf(m, __shfl_xor(m, 1));
      m = fmaxf(m, __shfl_xor(m, 2));
      m = fmaxf(m, __shfl_xor(m, 4));
      m = fmaxf(m, __shfl_xor(m, 8));
      float sum = 0.f;
#pragma unroll
      for (int j = 0; j < 8; ++j) {
        float p = __expf(accs[i][j][r] - m);
        accs[i][j][r] = p;
        sum += p;
      }
      sum += __shfl_xor(sum, 1);
      sum += __shfl_xor(sum, 2);
      sum += __shfl_xor(sum, 4);
      sum += __shfl_xor(sum, 8);
      linv[i][r] = 1.f / sum;
    }
    int rowb = m0 + i * 16 + quad * 4;
#pragma unroll
    for (int j = 0; j < 8; ++j)
#pragma unroll
      for (int r = 0; r < 4; ++r)
        Ps[(rowb + r) * 136 + j * 16 + l16] = (_Float16)accs[i][j][r];
  }
  __syncthreads();

  f32x4 acco[2][4];
#pragma unroll
  for (int i = 0; i < 2; ++i)
#pragma unroll
    for (int j = 0; j < 4; ++j) acco[i][j] = (f32x4){0.f, 0.f, 0.f, 0.f};

#pragma unroll
  for (int ks = 0; ks < 4; ++ks) {
    int k0 = ks * 32 + quad * 8;
    f16x8 pa[2], vf[4];
#pragma unroll
    for (int i = 0; i < 2; ++i)
      pa[i] = *(const f16x8*)&Ps[(m0 + i * 16 + l16) * 136 + k0];
#pragma unroll
    for (int j = 0; j < 4; ++j)
      vf[j] = *(const f16x8*)&Vt[(j * 16 + l16) * 136 + k0];
#pragma unroll
    for (int i = 0; i < 2; ++i)
#pragma unroll
      for (int j = 0; j < 4; ++j)
        acco[i][j] = __builtin_amdgcn_mfma_f32_16x16x32_f16(pa[i], vf[j], acco[i][j], 0, 0, 0);
  }

  _Float16* Cb = Ctx + (size_t)b * SEQ * HDIM + h * HEADD;
#pragma unroll
  for (int i = 0; i < 2; ++i)
#pragma unroll
    for (int j = 0; j < 4; ++j)
#pragma unroll
      for (int r = 0; r < 4; ++r) {
        int row = m0 + i * 16 + quad * 4 + r;
        int d = j * 16 + l16;
        Cb[(size_t)row * HDIM + d] = (_Float16)(acco[i][j][r] * linv[i][r]);
      }
}

// ---------------- residual + NP partials + layernorm ---------------------------
template <int NP>
__global__ __launch_bounds__(256) void resid_ln_kernel(
    const float* __restrict__ X, const float* __restrict__ P0,
    const float* __restrict__ P1,
    const float* __restrict__ Gall, const float* __restrict__ Ball,
    const int* __restrict__ eid, float* __restrict__ Out,
    _Float16* __restrict__ Out16) {
  int row = blockIdx.x, b = blockIdx.y, t = threadIdx.x;
  int e = eid[b];
  size_t off = ((size_t)b * SEQ + row) * HDIM;
  const float* x = X + off;
  const float* p0 = P0 + off;
  const float* p1 = (NP > 1) ? P1 + off : nullptr;
  float* o = Out + off;
  const float* g = Gall + (size_t)e * HDIM;
  const float* bb = Ball + (size_t)e * HDIM;

  __shared__ float buf[HDIM];
  __shared__ float red[256];

  float s = 0.f;
  for (int h = t; h < HDIM; h += 256) {
    float v = x[h] + p0[h];
    if (NP > 1) v += p1[h];
    buf[h] = v;
    s += v;
  }
  red[t] = s;
  __syncthreads();
  for (int off2 = 128; off2 > 0; off2 >>= 1) {
    if (t < off2) red[t] += red[t + off2];
    __syncthreads();
  }
  float mean = red[0] * (1.0f / HDIM);
  __syncthreads();

  float s2 = 0.f;
  for (int h = t; h < HDIM; h += 256) {
    float d = buf[h] - mean;
    s2 += d * d;
  }
  red[t] = s2;
  __syncthreads();
  for (int off2 = 128; off2 > 0; off2 >>= 1) {
    if (t < off2) red[t] += red[t + off2];
    __syncthreads();
  }
  float var = red[0] * (1.0f / HDIM);
  float rs = rsqrtf(var + 1e-12f);

  for (int h = t; h < HDIM; h += 256) {
    float v = (buf[h] - mean) * rs * g[h] + bb[h];
    o[h] = v;
    if (Out16) Out16[off + h] = (_Float16)v;
  }
}

// ------------------------------------------------------------------------------
extern "C" void kernel_launch(void* const* d_in, const int* in_sizes, int n_in,
                              void* d_out, int out_size, void* d_ws, size_t ws_size,
                              hipStream_t stream) {
  const float* hs   = (const float*)d_in[0];
  const float* mask = (const float*)d_in[1];
  const float* cen  = (const float*)d_in[2];
  const float* wq = (const float*)d_in[3];
  const float* wk = (const float*)d_in[4];
  const float* wv = (const float*)d_in[5];
  const float* wo = (const float*)d_in[6];
  const float* bq = (const float*)d_in[7];
  const float* bk = (const float*)d_in[8];
  const float* bv = (const float*)d_in[9];
  const float* bo = (const float*)d_in[10];
  const float* ln1g = (const float*)d_in[11];
  const float* ln1b = (const float*)d_in[12];
  const float* w1 = (const float*)d_in[13];
  const float* b1 = (const float*)d_in[14];
  const float* w2 = (const float*)d_in[15];
  const float* b2 = (const float*)d_in[16];
  const float* ln2g = (const float*)d_in[17];
  const float* ln2b = (const float*)d_in[18];
  float* out = (float*)d_out;

  const size_t sh = (size_t)SEQ * HDIM;
  const int DYNLDS = 81920;  // 80 KB (2 buffers x 40 KB) -> 2 blocks/CU

  static bool attr_done = false;
  if (!attr_done) {
    attr_done = true;
    auto* k1 = gemm_mfma8<1, 0, HDIM, 1>;
    auto* k2 = gemm_mfma8<0, 0, HDIM, 2>;
    auto* k3 = gemm_mfma8<1, 1, HDIM, 1>;
    auto* k4 = gemm_mfma8<0, 0, FFDIM, 2>;
    (void)hipFuncSetAttribute((const void*)k1, hipFuncAttributeMaxDynamicSharedMemorySize, DYNLDS);
    (void)hipFuncSetAttribute((const void*)k2, hipFuncAttributeMaxDynamicSharedMemorySize, DYNLDS);
    (void)hipFuncSetAttribute((const void*)k3, hipFuncAttributeMaxDynamicSharedMemorySize, DYNLDS);
    (void)hipFuncSetAttribute((const void*)k4, hipFuncAttributeMaxDynamicSharedMemorySize, DYNLDS);
  }

  char* p = (char*)d_ws;
  int* eid = (int*)p;                 p += 256;
  int* order = (int*)p;               p += 256;
  int* ord_eid = (int*)p;             p += 256;
  float* bqkv = (float*)p;            p += (size_t)NEXP * QKVN * 4;
  _Float16* Wqkvt = (_Float16*)p;     p += (size_t)NEXP * QKVN * HDIM * 2;
  _Float16* Wot = (_Float16*)p;       p += (size_t)NEXP * HDIM * HDIM * 2;
  _Float16* W1t = (_Float16*)p;       p += (size_t)NEXP * FFDIM * HDIM * 2;
  _Float16* W2t = (_Float16*)p;       p += (size_t)NEXP * HDIM * FFDIM * 2;
  _Float16* x16 = (_Float16*)p;       p += (size_t)NB * sh * 2;

  char* region = p;                   p += (size_t)NB * SEQ * QKVN * 2;
  _Float16* ctx16 = (_Float16*)p;     p += (size_t)NB * sh * 2;
  float* aof = (float*)p;             p += (size_t)NB * sh * 4;
  _Float16* ao16 = (_Float16*)p;      p += (size_t)NB * sh * 2;
  char* ffreg = p;                    p += (size_t)NB * SEQ * FFDIM * 2;

  float* woparts = (float*)ffreg;
  float* w2parts = (float*)region;
  _Float16* ff16 = (_Float16*)ffreg;

  // 1. routing + hs->f16
  route_cvt_kernel<<<NB, 256, 0, stream>>>(hs, cen, eid, x16);
  // 2. weight prep (single launch)
  prep_weights<<<dim3(6949, NEXP), 256, 0, stream>>>(
      wq, wk, wv, wo, w1, w2, bq, bk, bv,
      Wqkvt, Wot, W1t, W2t, bqkv, eid, order, ord_eid);
  // 3. QKV fused -> region (f16): 12 col-tiles x 64 samples = 768 blocks
  gemm_mfma8<1, 0, HDIM, 1><<<dim3((QKVN / 192) * NB), 512, DYNLDS, stream>>>(
      x16, Wqkvt, bqkv, order, ord_eid, region, QKVN);
  // 4. attention -> ctx16
  attn_mfma<<<dim3(NHEAD, NB), 256, 0, stream>>>(
      (const _Float16*)region, mask, ctx16);
  // 5. wo split-K=2 -> woparts (ffreg): 4 x 64 x 2 = 512 blocks
  gemm_mfma8<0, 0, HDIM, 2><<<dim3((HDIM / 192) * NB * 2), 512, DYNLDS, stream>>>(
      ctx16, Wot, bo, order, ord_eid, woparts, HDIM);
  // 6. LN1
  resid_ln_kernel<2><<<dim3(SEQ, NB), 256, 0, stream>>>(
      hs, woparts, woparts + (size_t)NB * sh, ln1g, ln1b, eid, aof, ao16);
  // 7. w1 + fast GELU -> ff16: 16 col-tiles x 64 = 1024 blocks
  gemm_mfma8<1, 1, HDIM, 1><<<dim3((FFDIM / 192) * NB), 512, DYNLDS, stream>>>(
      ao16, W1t, b1, order, ord_eid, ff16, FFDIM);
  // 8. w2 split-K=2 -> w2parts: 512 blocks
  gemm_mfma8<0, 0, FFDIM, 2><<<dim3((HDIM / 192) * NB * 2), 512, DYNLDS, stream>>>(
      ff16, W2t, b2, order, ord_eid, w2parts, HDIM);
  // 9. LN2 -> out
  resid_ln_kernel<2><<<dim3(SEQ, NB), 256, 0, stream>>>(
      aof, w2parts, w2parts + (size_t)NB * sh, ln2g, ln2b, eid, out,
      (_Float16*)nullptr);
}

// Round 6
// 420.707 us; speedup vs baseline: 1.1619x; 1.0694x over previous
//
#include <hip/hip_runtime.h>
#include <hip/hip_bf16.h>
#include <math.h>

#define HDIM 768
#define NHEAD 12
#define HEADD 64
#define FFDIM 3072
#define NEXP 4
#define SEQ 128
#define NB 64
#define QKVN 2304

typedef __attribute__((ext_vector_type(8))) _Float16 f16x8;
typedef __attribute__((ext_vector_type(4))) _Float16 f16x4;
typedef __attribute__((ext_vector_type(4))) float f32x4;

// s_waitcnt encodings: vm low [3:0], exp [6:4], lgkm [11:8], vm high [15:14]
#define WAITVM0 __builtin_amdgcn_s_waitcnt(0xF70)    // vmcnt(0)
#define WAITLGKM0 __builtin_amdgcn_s_waitcnt(0xC07F) // lgkmcnt(0), vm untouched

// gelu_tanh(x) = x * sigmoid(1.5957691*x*(1+0.044715x^2)) — exact rewrite
__device__ __forceinline__ float gelu_fast(float x) {
  float t = -1.5957691216057308f * x * __builtin_fmaf(0.044715f * x, x, 1.0f);
  return x * __builtin_amdgcn_rcpf(1.0f + __expf(t));
}

__device__ __forceinline__ void gld_lds16(const void* g, void* l) {
  __builtin_amdgcn_global_load_lds(
      (const __attribute__((address_space(1))) unsigned int*)g,
      (__attribute__((address_space(3))) unsigned int*)l, 16, 0, 0);
}

// ---------------- routing part 1: convert + slice-partial column sums --------
// r5: route_cvt ran 64 blocks (25% of CUs) over a 75MB stream. Split into
// 256 blocks (4 slices x 64 samples), each handling 32 rows: convert fp32->f16
// (float4 in, f16x4 out) + per-slice column sums to workspace (no atomics).
__global__ __launch_bounds__(256) void route_cvt_part(
    const float* __restrict__ hs, float* __restrict__ psum,
    _Float16* __restrict__ x16) {
  int s = blockIdx.x, b = blockIdx.y, t = threadIdx.x;
  const float* xb = hs + ((size_t)b * SEQ + s * 32) * HDIM;
  _Float16* ob = x16 + ((size_t)b * SEQ + s * 32) * HDIM;
  if (t < 192) {
    float p0 = 0.f, p1 = 0.f, p2 = 0.f, p3 = 0.f;
    for (int sq = 0; sq < 32; ++sq) {
      float4 v = ((const float4*)(xb + (size_t)sq * HDIM))[t];
      p0 += v.x; p1 += v.y; p2 += v.z; p3 += v.w;
      f16x4 h = {(_Float16)v.x, (_Float16)v.y, (_Float16)v.z, (_Float16)v.w};
      *(f16x4*)(ob + (size_t)sq * HDIM + t * 4) = h;
    }
    float* ps = psum + ((size_t)b * 4 + s) * HDIM + t * 4;
    ps[0] = p0; ps[1] = p1; ps[2] = p2; ps[3] = p3;
  }
}

// ---------------- routing part 2: distances + argmin --------------------------
__global__ __launch_bounds__(256) void route_finish(
    const float* __restrict__ psum, const float* __restrict__ centers,
    int* __restrict__ eid) {
  int b = blockIdx.x, t = threadIdx.x;
  __shared__ float dist[NEXP];
  if (t < NEXP) dist[t] = 0.f;
  __syncthreads();
  const float* ps = psum + (size_t)b * 4 * HDIM;
  float pe[NEXP] = {0.f, 0.f, 0.f, 0.f};
  for (int h = t; h < HDIM; h += 256) {
    float v = (ps[h] + ps[HDIM + h] + ps[2 * HDIM + h] + ps[3 * HDIM + h]) *
              (1.0f / SEQ);
#pragma unroll
    for (int e = 0; e < NEXP; ++e) {
      float d = v - centers[e * HDIM + h];
      pe[e] += d * d;
    }
  }
#pragma unroll
  for (int e = 0; e < NEXP; ++e) atomicAdd(&dist[e], pe[e]);
  __syncthreads();
  if (t == 0) {
    int best = 0; float bv = dist[0];
    for (int e = 1; e < NEXP; ++e) if (dist[e] < bv) { bv = dist[e]; best = e; }
    eid[b] = best;
  }
}

// ---------------- weight prep: 64x64 tiles, vectorized both sides -------------
// r5 counters: prep_weights was the top dispatch (63.5us @ 1.78TB/s, 22% HBM)
// — ideal traffic is ~27us. Cause: scalar 4B loads + scalar 2B stores in 64B
// segments (old 32x32 tile). New: 64x64 tile; phase1 float4 coalesced reads
// (256B/row-segment) -> f16 LDS [64][72] transposed; phase2 f16x8 LDS reads +
// 16B/lane stores, lanes 0-7 = one 128B-contiguous row segment (full write
// coalescing). LDS conflicts (<=8-way on 8 wave-instrs) are not on the
// critical path of this streaming kernel.
__device__ __forceinline__ void tr_tile64(const float* __restrict__ ip,
                                          _Float16* __restrict__ op,
                                          int K, int N, int nb, int kb,
                                          _Float16 (*tile)[72], int t) {
  int kk = t >> 4;           // 0..15
  int nn = (t & 15) * 4;     // 0..60
#pragma unroll
  for (int r = 0; r < 4; ++r) {
    int k = kk + r * 16;
    float4 v = *(const float4*)(ip + (size_t)(kb + k) * N + nb + nn);
    tile[nn + 0][k] = (_Float16)v.x;
    tile[nn + 1][k] = (_Float16)v.y;
    tile[nn + 2][k] = (_Float16)v.z;
    tile[nn + 3][k] = (_Float16)v.w;
  }
  __syncthreads();
  int j8 = (t & 7) * 8;      // k-octet
  int n0 = t >> 3;           // 0..31
#pragma unroll
  for (int r = 0; r < 2; ++r) {
    int n = n0 + r * 32;
    *(f16x8*)(op + (size_t)(nb + n) * K + kb + j8) = *(const f16x8*)&tile[n][j8];
  }
}

__global__ __launch_bounds__(256) void prep_weights(
    const float* __restrict__ wq, const float* __restrict__ wk,
    const float* __restrict__ wv, const float* __restrict__ wo,
    const float* __restrict__ w1, const float* __restrict__ w2,
    const float* __restrict__ bq, const float* __restrict__ bk,
    const float* __restrict__ bv,
    _Float16* __restrict__ Wqkvt, _Float16* __restrict__ Wot,
    _Float16* __restrict__ W1t, _Float16* __restrict__ W2t,
    float* __restrict__ bqkv, const int* __restrict__ eid,
    int* __restrict__ order, int* __restrict__ ord_eid) {
  __shared__ __align__(16) _Float16 tile[64][72];  // 18 KB
  int x = blockIdx.x, e = blockIdx.y, t = threadIdx.x;

  if (x < 432) {               // wq/wk/wv: 3 x 144 tiles (12x12)
    int which = x / 144, local = x % 144;
    const float* src = (which == 0) ? wq : (which == 1) ? wk : wv;
    tr_tile64(src + (size_t)e * HDIM * HDIM,
              Wqkvt + (size_t)which * HDIM * HDIM + (size_t)e * QKVN * HDIM,
              HDIM, HDIM, (local % 12) * 64, (local / 12) * 64, tile, t);
  } else if (x < 576) {        // wo: 144 tiles
    int local = x - 432;
    tr_tile64(wo + (size_t)e * HDIM * HDIM, Wot + (size_t)e * HDIM * HDIM,
              HDIM, HDIM, (local % 12) * 64, (local / 12) * 64, tile, t);
  } else if (x < 1152) {       // w1: K=768, N=3072: 48x12 = 576 tiles
    int local = x - 576;
    tr_tile64(w1 + (size_t)e * HDIM * FFDIM, W1t + (size_t)e * FFDIM * HDIM,
              HDIM, FFDIM, (local % 48) * 64, (local / 48) * 64, tile, t);
  } else if (x < 1728) {       // w2: K=3072, N=768: 12x48 = 576 tiles
    int local = x - 1152;
    tr_tile64(w2 + (size_t)e * FFDIM * HDIM, W2t + (size_t)e * HDIM * FFDIM,
              FFDIM, HDIM, (local % 12) * 64, (local / 12) * 64, tile, t);
  } else if (x < 1737) {       // fused qkv bias (per expert e)
    int n = (x - 1728) * 256 + t;
    if (n < QKVN) {
      float v = (n < HDIM) ? bq[e * HDIM + n]
              : (n < 2 * HDIM) ? bk[e * HDIM + n - HDIM]
                               : bv[e * HDIM + n - 2 * HDIM];
      bqkv[e * QKVN + n] = v;
    }
  } else {                     // expert-sorted sample order
    if (e == 0 && t == 0) {
      int n = 0;
      for (int ee = 0; ee < NEXP; ++ee)
        for (int b = 0; b < NB; ++b)
          if (eid[b] == ee) { order[n] = b; ord_eid[n] = ee; n++; }
    }
  }
}

// ---------------- MFMA GEMM: 128x192 tile, st_16x32 LDS layout ----------------
// (r5-proven: layout fix dropped all GEMMs below prep_weights; unchanged)
template <int OUT_F16, int GELU, int KDIM, int SPLITK>
__global__ __launch_bounds__(512, 4) void gemm_mfma8(
    const _Float16* __restrict__ A, const _Float16* __restrict__ Wt,
    const float* __restrict__ Ball, const int* __restrict__ order,
    const int* __restrict__ ord_eid, void* __restrict__ Cv, int N) {
  constexpr int K = KDIM;
  constexpr int Kp = KDIM / SPLITK;
  constexpr int NT = Kp / 64;
  extern __shared__ __align__(16) char dynlds[];
  _Float16* lds = (_Float16*)dynlds;

  int GX = N / 192;
  int nwg = GX * NB * SPLITK;
  int L = blockIdx.x;
  int r = (L & 7) * (nwg >> 3) + (L >> 3);
  int z = r & 63;
  int rest = r >> 6;
  int kz = rest % SPLITK;
  int c = rest / SPLITK;
  int b = order[z];
  int e = ord_eid[z];
  int col0 = c * 192;
  int kbeg = kz * Kp;

  int t = threadIdx.x;
  int lane = t & 63, w = t >> 6;
  int quad = lane >> 4, l16 = lane & 15;
  int wr64 = (w >> 2) * 64;
  int wc48 = (w & 3) * 48;

  int srow = t >> 3;
  int scol = ((t & 7) * 8) ^ ((t & 32) >> 1);

  const _Float16* srcA = A + (size_t)b * SEQ * K + kbeg + (size_t)srow * K + scol;
  const _Float16* srcB = Wt + (size_t)e * N * K + (size_t)(col0 + srow) * K + kbeg + scol;

  auto issueP0 = [&](int Tn) {
    _Float16* dst = lds + (size_t)(Tn & 1) * 20480;
    int goff = Tn * 64;
    gld_lds16(srcA + goff, dst + t * 8);
    gld_lds16(srcA + (size_t)64 * K + goff, dst + 4096 + t * 8);
    gld_lds16(srcB + goff, dst + 8192 + t * 8);
  };
  auto issueP1 = [&](int Tn) {
    _Float16* dst = lds + (size_t)(Tn & 1) * 20480;
    int goff = Tn * 64;
    gld_lds16(srcB + (size_t)64 * K + goff, dst + 12288 + t * 8);
    gld_lds16(srcB + (size_t)128 * K + goff, dst + 16384 + t * 8);
  };

  f32x4 acc[4][3];
#pragma unroll
  for (int i = 0; i < 4; ++i)
#pragma unroll
    for (int j = 0; j < 3; ++j) acc[i][j] = (f32x4){0.f, 0.f, 0.f, 0.f};

  int ck = (quad * 8) ^ ((l16 & 4) << 2);

  issueP0(0);
  issueP1(0);
  WAITVM0;
  __builtin_amdgcn_s_barrier();

  for (int T = 0; T < NT; ++T) {
    const _Float16* Ab = lds + (size_t)(T & 1) * 20480;
    const _Float16* Bb = Ab + 8192;

    {
      f16x8 af[4], bf[3];
#pragma unroll
      for (int i = 0; i < 4; ++i)
        af[i] = *(const f16x8*)&Ab[(wr64 + i * 16 + l16) * 64 + ck];
#pragma unroll
      for (int j = 0; j < 3; ++j)
        bf[j] = *(const f16x8*)&Bb[(wc48 + j * 16 + l16) * 64 + ck];
      if (T + 1 < NT) issueP0(T + 1);
      __builtin_amdgcn_s_barrier();
      WAITLGKM0;
      __builtin_amdgcn_s_setprio(1);
#pragma unroll
      for (int i = 0; i < 4; ++i)
#pragma unroll
        for (int j = 0; j < 3; ++j)
          acc[i][j] = __builtin_amdgcn_mfma_f32_16x16x32_f16(af[i], bf[j], acc[i][j], 0, 0, 0);
      __builtin_amdgcn_s_setprio(0);
    }

    {
      f16x8 af[4], bf[3];
#pragma unroll
      for (int i = 0; i < 4; ++i)
        af[i] = *(const f16x8*)&Ab[(wr64 + i * 16 + l16) * 64 + 32 + ck];
#pragma unroll
      for (int j = 0; j < 3; ++j)
        bf[j] = *(const f16x8*)&Bb[(wc48 + j * 16 + l16) * 64 + 32 + ck];
      if (T + 1 < NT) issueP1(T + 1);
      __builtin_amdgcn_s_barrier();
      WAITLGKM0;
      __builtin_amdgcn_s_setprio(1);
#pragma unroll
      for (int i = 0; i < 4; ++i)
#pragma unroll
        for (int j = 0; j < 3; ++j)
          acc[i][j] = __builtin_amdgcn_mfma_f32_16x16x32_f16(af[i], bf[j], acc[i][j], 0, 0, 0);
      __builtin_amdgcn_s_setprio(0);
    }

    if (T + 1 < NT) {
      WAITVM0;
      __builtin_amdgcn_s_barrier();
    }
  }

  const float* bias = Ball + (size_t)e * N;

  if (OUT_F16) {
    _Float16* Ch = (_Float16*)Cv + (size_t)b * SEQ * N;
#pragma unroll
    for (int i = 0; i < 4; ++i)
#pragma unroll
      for (int j = 0; j < 3; ++j) {
        int col = col0 + wc48 + j * 16 + l16;
        float bv = bias[col];
#pragma unroll
        for (int r2 = 0; r2 < 4; ++r2) {
          int row = wr64 + i * 16 + quad * 4 + r2;
          float v = acc[i][j][r2] + bv;
          if (GELU) v = gelu_fast(v);
          Ch[(size_t)row * N + col] = (_Float16)v;
        }
      }
  } else {
    float* Cf = (float*)Cv + (size_t)kz * NB * SEQ * N + (size_t)b * SEQ * N;
    float bscale = (kz == 0) ? 1.f : 0.f;
#pragma unroll
    for (int i = 0; i < 4; ++i)
#pragma unroll
      for (int j = 0; j < 3; ++j) {
        int col = col0 + wc48 + j * 16 + l16;
        float bv = bias[col] * bscale;
#pragma unroll
        for (int r2 = 0; r2 < 4; ++r2) {
          int row = wr64 + i * 16 + quad * 4 + r2;
          Cf[(size_t)row * N + col] = acc[i][j][r2] + bv;
        }
      }
  }
}

// ---------------- MFMA attention: one block per (head, sample) ----------------
__global__ __launch_bounds__(256) void attn_mfma(
    const _Float16* __restrict__ QKV, const float* __restrict__ mask,
    _Float16* __restrict__ Ctx) {
  int h = blockIdx.x, b = blockIdx.y;
  int t = threadIdx.x;
  int w = t >> 6, lane = t & 63, quad = lane >> 4, l16 = lane & 15;

  __shared__ __align__(16) char smem[54784];
  _Float16* Qs = (_Float16*)smem;                 // [128][72]
  _Float16* Ks = (_Float16*)(smem + 18432);       // [128][72]
  _Float16* Ps = (_Float16*)smem;                 // [128][136]
  _Float16* Vt = (_Float16*)(smem + 36864);       // [64][136]
  float* mrow = (float*)(smem + 54272);           // [128]

  const _Float16* Qb = QKV + (size_t)b * SEQ * QKVN + h * HEADD;
  const _Float16* Kb = Qb + HDIM;
  const _Float16* Vb = Qb + 2 * HDIM;

#pragma unroll
  for (int it = 0; it < 4; ++it) {
    int chunk = t + it * 256;
    int row = chunk >> 3, c = chunk & 7;
    *(f16x8*)&Qs[row * 72 + c * 8] = *(const f16x8*)(Qb + (size_t)row * QKVN + c * 8);
    *(f16x8*)&Ks[row * 72 + c * 8] = *(const f16x8*)(Kb + (size_t)row * QKVN + c * 8);
  }
  {
    int vc = t & 7, vjp0 = t >> 3;
#pragma unroll
    for (int it = 0; it < 2; ++it) {
      int jp = vjp0 + it * 32;
      f16x8 v0 = *(const f16x8*)(Vb + (size_t)(2 * jp) * QKVN + vc * 8);
      f16x8 v1 = *(const f16x8*)(Vb + (size_t)(2 * jp + 1) * QKVN + vc * 8);
#pragma unroll
      for (int i = 0; i < 8; ++i) {
        int d = vc * 8 + i;
        unsigned ua = __builtin_bit_cast(unsigned short, (_Float16)v0[i]);
        unsigned ub = __builtin_bit_cast(unsigned short, (_Float16)v1[i]);
        ((unsigned*)Vt)[d * 68 + jp] = ua | (ub << 16);
      }
    }
  }
  if (t < SEQ) mrow[t] = mask[(size_t)b * SEQ + t];
  __syncthreads();

  int m0 = w * 32;
  f32x4 accs[2][8];
#pragma unroll
  for (int i = 0; i < 2; ++i)
#pragma unroll
    for (int j = 0; j < 8; ++j) accs[i][j] = (f32x4){0.f, 0.f, 0.f, 0.f};

#pragma unroll
  for (int ks = 0; ks < 2; ++ks) {
    int k0 = ks * 32 + quad * 8;
    f16x8 af[2], bf[8];
#pragma unroll
    for (int i = 0; i < 2; ++i)
      af[i] = *(const f16x8*)&Qs[(m0 + i * 16 + l16) * 72 + k0];
#pragma unroll
    for (int j = 0; j < 8; ++j)
      bf[j] = *(const f16x8*)&Ks[(j * 16 + l16) * 72 + k0];
#pragma unroll
    for (int i = 0; i < 2; ++i)
#pragma unroll
      for (int j = 0; j < 8; ++j)
        accs[i][j] = __builtin_amdgcn_mfma_f32_16x16x32_f16(af[i], bf[j], accs[i][j], 0, 0, 0);
  }
  __syncthreads();

  float mv[8];
#pragma unroll
  for (int j = 0; j < 8; ++j) mv[j] = mrow[j * 16 + l16];

  float linv[2][4];
#pragma unroll
  for (int i = 0; i < 2; ++i) {
#pragma unroll
    for (int j = 0; j < 8; ++j)
#pragma unroll
      for (int r = 0; r < 4; ++r)
        accs[i][j][r] = accs[i][j][r] * 0.125f + mv[j];
#pragma unroll
    for (int r = 0; r < 4; ++r) {
      float m = accs[i][0][r];
#pragma unroll
      for (int j = 1; j < 8; ++j) m = fmaxf(m, accs[i][j][r]);
      m = fmaxf(m, __shfl_xor(m, 1));
      m = fmaxf(m, __shfl_xor(m, 2));
      m = fmaxf(m, __shfl_xor(m, 4));
      m = fmaxf(m, __shfl_xor(m, 8));
      float sum = 0.f;
#pragma unroll
      for (int j = 0; j < 8; ++j) {
        float p = __expf(accs[i][j][r] - m);
        accs[i][j][r] = p;
        sum += p;
      }
      sum += __shfl_xor(sum, 1);
      sum += __shfl_xor(sum, 2);
      sum += __shfl_xor(sum, 4);
      sum += __shfl_xor(sum, 8);
      linv[i][r] = 1.f / sum;
    }
    int rowb = m0 + i * 16 + quad * 4;
#pragma unroll
    for (int j = 0; j < 8; ++j)
#pragma unroll
      for (int r = 0; r < 4; ++r)
        Ps[(rowb + r) * 136 + j * 16 + l16] = (_Float16)accs[i][j][r];
  }
  __syncthreads();

  f32x4 acco[2][4];
#pragma unroll
  for (int i = 0; i < 2; ++i)
#pragma unroll
    for (int j = 0; j < 4; ++j) acco[i][j] = (f32x4){0.f, 0.f, 0.f, 0.f};

#pragma unroll
  for (int ks = 0; ks < 4; ++ks) {
    int k0 = ks * 32 + quad * 8;
    f16x8 pa[2], vf[4];
#pragma unroll
    for (int i = 0; i < 2; ++i)
      pa[i] = *(const f16x8*)&Ps[(m0 + i * 16 + l16) * 136 + k0];
#pragma unroll
    for (int j = 0; j < 4; ++j)
      vf[j] = *(const f16x8*)&Vt[(j * 16 + l16) * 136 + k0];
#pragma unroll
    for (int i = 0; i < 2; ++i)
#pragma unroll
      for (int j = 0; j < 4; ++j)
        acco[i][j] = __builtin_amdgcn_mfma_f32_16x16x32_f16(pa[i], vf[j], acco[i][j], 0, 0, 0);
  }

  _Float16* Cb = Ctx + (size_t)b * SEQ * HDIM + h * HEADD;
#pragma unroll
  for (int i = 0; i < 2; ++i)
#pragma unroll
    for (int j = 0; j < 4; ++j)
#pragma unroll
      for (int r = 0; r < 4; ++r) {
        int row = m0 + i * 16 + quad * 4 + r;
        int d = j * 16 + l16;
        Cb[(size_t)row * HDIM + d] = (_Float16)(acco[i][j][r] * linv[i][r]);
      }
}

// ---------------- residual + NP partials + layernorm ---------------------------
template <int NP>
__global__ __launch_bounds__(256) void resid_ln_kernel(
    const float* __restrict__ X, const float* __restrict__ P0,
    const float* __restrict__ P1,
    const float* __restrict__ Gall, const float* __restrict__ Ball,
    const int* __restrict__ eid, float* __restrict__ Out,
    _Float16* __restrict__ Out16) {
  int row = blockIdx.x, b = blockIdx.y, t = threadIdx.x;
  int e = eid[b];
  size_t off = ((size_t)b * SEQ + row) * HDIM;
  const float* x = X + off;
  const float* p0 = P0 + off;
  const float* p1 = (NP > 1) ? P1 + off : nullptr;
  float* o = Out + off;
  const float* g = Gall + (size_t)e * HDIM;
  const float* bb = Ball + (size_t)e * HDIM;

  __shared__ float buf[HDIM];
  __shared__ float red[256];

  float s = 0.f;
  for (int h = t; h < HDIM; h += 256) {
    float v = x[h] + p0[h];
    if (NP > 1) v += p1[h];
    buf[h] = v;
    s += v;
  }
  red[t] = s;
  __syncthreads();
  for (int off2 = 128; off2 > 0; off2 >>= 1) {
    if (t < off2) red[t] += red[t + off2];
    __syncthreads();
  }
  float mean = red[0] * (1.0f / HDIM);
  __syncthreads();

  float s2 = 0.f;
  for (int h = t; h < HDIM; h += 256) {
    float d = buf[h] - mean;
    s2 += d * d;
  }
  red[t] = s2;
  __syncthreads();
  for (int off2 = 128; off2 > 0; off2 >>= 1) {
    if (t < off2) red[t] += red[t + off2];
    __syncthreads();
  }
  float var = red[0] * (1.0f / HDIM);
  float rs = rsqrtf(var + 1e-12f);

  for (int h = t; h < HDIM; h += 256) {
    float v = (buf[h] - mean) * rs * g[h] + bb[h];
    o[h] = v;
    if (Out16) Out16[off + h] = (_Float16)v;
  }
}

// ------------------------------------------------------------------------------
extern "C" void kernel_launch(void* const* d_in, const int* in_sizes, int n_in,
                              void* d_out, int out_size, void* d_ws, size_t ws_size,
                              hipStream_t stream) {
  const float* hs   = (const float*)d_in[0];
  const float* mask = (const float*)d_in[1];
  const float* cen  = (const float*)d_in[2];
  const float* wq = (const float*)d_in[3];
  const float* wk = (const float*)d_in[4];
  const float* wv = (const float*)d_in[5];
  const float* wo = (const float*)d_in[6];
  const float* bq = (const float*)d_in[7];
  const float* bk = (const float*)d_in[8];
  const float* bv = (const float*)d_in[9];
  const float* bo = (const float*)d_in[10];
  const float* ln1g = (const float*)d_in[11];
  const float* ln1b = (const float*)d_in[12];
  const float* w1 = (const float*)d_in[13];
  const float* b1 = (const float*)d_in[14];
  const float* w2 = (const float*)d_in[15];
  const float* b2 = (const float*)d_in[16];
  const float* ln2g = (const float*)d_in[17];
  const float* ln2b = (const float*)d_in[18];
  float* out = (float*)d_out;

  const size_t sh = (size_t)SEQ * HDIM;
  const int DYNLDS = 81920;  // 80 KB (2 buffers x 40 KB) -> 2 blocks/CU

  static bool attr_done = false;
  if (!attr_done) {
    attr_done = true;
    auto* k1 = gemm_mfma8<1, 0, HDIM, 1>;
    auto* k2 = gemm_mfma8<0, 0, HDIM, 2>;
    auto* k3 = gemm_mfma8<1, 1, HDIM, 1>;
    auto* k4 = gemm_mfma8<0, 0, FFDIM, 2>;
    (void)hipFuncSetAttribute((const void*)k1, hipFuncAttributeMaxDynamicSharedMemorySize, DYNLDS);
    (void)hipFuncSetAttribute((const void*)k2, hipFuncAttributeMaxDynamicSharedMemorySize, DYNLDS);
    (void)hipFuncSetAttribute((const void*)k3, hipFuncAttributeMaxDynamicSharedMemorySize, DYNLDS);
    (void)hipFuncSetAttribute((const void*)k4, hipFuncAttributeMaxDynamicSharedMemorySize, DYNLDS);
  }

  char* p = (char*)d_ws;
  int* eid = (int*)p;                 p += 256;
  int* order = (int*)p;               p += 256;
  int* ord_eid = (int*)p;             p += 256;
  float* psum = (float*)p;            p += (size_t)NB * 4 * HDIM * 4;
  float* bqkv = (float*)p;            p += (size_t)NEXP * QKVN * 4;
  _Float16* Wqkvt = (_Float16*)p;     p += (size_t)NEXP * QKVN * HDIM * 2;
  _Float16* Wot = (_Float16*)p;       p += (size_t)NEXP * HDIM * HDIM * 2;
  _Float16* W1t = (_Float16*)p;       p += (size_t)NEXP * FFDIM * HDIM * 2;
  _Float16* W2t = (_Float16*)p;       p += (size_t)NEXP * HDIM * FFDIM * 2;
  _Float16* x16 = (_Float16*)p;       p += (size_t)NB * sh * 2;

  char* region = p;                   p += (size_t)NB * SEQ * QKVN * 2;
  _Float16* ctx16 = (_Float16*)p;     p += (size_t)NB * sh * 2;
  float* aof = (float*)p;             p += (size_t)NB * sh * 4;
  _Float16* ao16 = (_Float16*)p;      p += (size_t)NB * sh * 2;
  char* ffreg = p;                    p += (size_t)NB * SEQ * FFDIM * 2;

  float* woparts = (float*)ffreg;
  float* w2parts = (float*)region;
  _Float16* ff16 = (_Float16*)ffreg;

  // 1a. convert + slice-partial sums (256 blocks)
  route_cvt_part<<<dim3(4, NB), 256, 0, stream>>>(hs, psum, x16);
  // 1b. routing distances + argmin
  route_finish<<<NB, 256, 0, stream>>>(psum, cen, eid);
  // 2. weight prep (64x64 vectorized tiles)
  prep_weights<<<dim3(1738, NEXP), 256, 0, stream>>>(
      wq, wk, wv, wo, w1, w2, bq, bk, bv,
      Wqkvt, Wot, W1t, W2t, bqkv, eid, order, ord_eid);
  // 3. QKV fused -> region (f16): 12 col-tiles x 64 samples = 768 blocks
  gemm_mfma8<1, 0, HDIM, 1><<<dim3((QKVN / 192) * NB), 512, DYNLDS, stream>>>(
      x16, Wqkvt, bqkv, order, ord_eid, region, QKVN);
  // 4. attention -> ctx16
  attn_mfma<<<dim3(NHEAD, NB), 256, 0, stream>>>(
      (const _Float16*)region, mask, ctx16);
  // 5. wo split-K=2 -> woparts (ffreg): 512 blocks
  gemm_mfma8<0, 0, HDIM, 2><<<dim3((HDIM / 192) * NB * 2), 512, DYNLDS, stream>>>(
      ctx16, Wot, bo, order, ord_eid, woparts, HDIM);
  // 6. LN1
  resid_ln_kernel<2><<<dim3(SEQ, NB), 256, 0, stream>>>(
      hs, woparts, woparts + (size_t)NB * sh, ln1g, ln1b, eid, aof, ao16);
  // 7. w1 + fast GELU -> ff16: 1024 blocks
  gemm_mfma8<1, 1, HDIM, 1><<<dim3((FFDIM / 192) * NB), 512, DYNLDS, stream>>>(
      ao16, W1t, b1, order, ord_eid, ff16, FFDIM);
  // 8. w2 split-K=2 -> w2parts: 512 blocks
  gemm_mfma8<0, 0, FFDIM, 2><<<dim3((HDIM / 192) * NB * 2), 512, DYNLDS, stream>>>(
      ff16, W2t, b2, order, ord_eid, w2parts, HDIM);
  // 9. LN2 -> out
  resid_ln_kernel<2><<<dim3(SEQ, NB), 256, 0, stream>>>(
      aof, w2parts, w2parts + (size_t)NB * sh, ln2g, ln2b, eid, out,
      (_Float16*)nullptr);
}